// Round 2
// baseline (717.120 us; speedup 1.0000x reference)
//
#include <hip/hip_runtime.h>
#include <hip/hip_bf16.h>

// Causal MHA forward, B=2 H=16 S=2048 DK=64, fp32 in/out.
// Flash-attention with bf16 MFMA (16x16x32), S^T orientation:
//   S^T = K.Q^T  (A=K-frag, B=Q-frag)  -> stats per m at lane&15
//   O^T = V^T.P^T (A=V^T-frag, B=P-frag) -> col=lane&15=m matches stats
// Block = 256 thr (4 waves x 16 q-rows = 64 q rows), key tiles of 32 staged
// in LDS (bf16) shared by the 4 waves.

using bf16x8 = __attribute__((ext_vector_type(8))) short;
using f32x4  = __attribute__((ext_vector_type(4))) float;

#define SEQ 2048
#define DKK 64

__device__ __forceinline__ short f2bf(float f) {
    union { float f; unsigned u; } v; v.f = f;
    unsigned r = v.u + 0x7fffu + ((v.u >> 16) & 1u);   // RNE
    return (short)(r >> 16);
}

__global__ __launch_bounds__(256, 4)
void fa_fwd(const float* __restrict__ Qg, const float* __restrict__ Kg,
            const float* __restrict__ Vg, float* __restrict__ Og) {
    // K tile: 32 keys x 64 d, bf16, row stride 72 (b128 frag reads bank-even)
    __shared__ short Kt[32 * 72];
    // V^T tile: 64 d x 32 keys, bf16, row stride 40 (b128 frag reads bank-even)
    __shared__ short Vt[64 * 40];
    // P scratch, per wave: 16 m x 32 n, bf16, stride 40
    __shared__ short Ps[4 * 16 * 40];

    const int qblk = (int)gridDim.x - 1 - (int)blockIdx.x;  // heavy blocks first
    const int bh   = blockIdx.y;
    const int qb0  = qblk * 64;
    const int tid  = threadIdx.x;
    const int lane = tid & 63;
    const int w    = tid >> 6;
    const int m16  = lane & 15;
    const int quad = lane >> 4;

    const size_t hoff = (size_t)bh * SEQ * DKK;
    const float* Qh = Qg + hoff;
    const float* Kh = Kg + hoff;
    const float* Vh = Vg + hoff;
    float*       Oh = Og + hoff;

    const int qb   = qb0 + 16 * w;     // this wave's q rows
    const int qrow = qb + m16;

    // Q fragments (B-operand layout): qf[h][j] = Q[qrow][32h + 8*quad + j]
    bf16x8 qf[2];
    {
        const float* qp = Qh + (size_t)qrow * DKK + quad * 8;
        #pragma unroll
        for (int h = 0; h < 2; ++h) {
            f32x4 a = *(const f32x4*)(qp + 32 * h);
            f32x4 b = *(const f32x4*)(qp + 32 * h + 4);
            bf16x8 f;
            f[0] = f2bf(a[0]); f[1] = f2bf(a[1]); f[2] = f2bf(a[2]); f[3] = f2bf(a[3]);
            f[4] = f2bf(b[0]); f[5] = f2bf(b[1]); f[6] = f2bf(b[2]); f[7] = f2bf(b[3]);
            qf[h] = f;
        }
    }

    float mrun = -1e30f, lrun = 0.f;
    f32x4 acc[4];
    {
        f32x4 z = {0.f, 0.f, 0.f, 0.f};
        #pragma unroll
        for (int c = 0; c < 4; ++c) acc[c] = z;
    }

    const int T = 2 * qblk + 2;   // key tiles of 32 covering keys 0..qb0+63
    for (int t = 0; t < T; ++t) {
        const int kb = t * 32;
        __syncthreads();
        // ---- stage K tile (coalesced f32x4 reads, b128 LDS writes, bank-even)
        {
            const int n = tid >> 3, c = tid & 7;
            const float* sp = Kh + (size_t)(kb + n) * DKK + c * 8;
            f32x4 a = *(const f32x4*)sp;
            f32x4 b = *(const f32x4*)(sp + 4);
            bf16x8 f;
            f[0] = f2bf(a[0]); f[1] = f2bf(a[1]); f[2] = f2bf(a[2]); f[3] = f2bf(a[3]);
            f[4] = f2bf(b[0]); f[5] = f2bf(b[1]); f[6] = f2bf(b[2]); f[7] = f2bf(b[3]);
            *(bf16x8*)&Kt[n * 72 + c * 8] = f;
        }
        // ---- stage V^T tile (pair-packed b32 LDS writes, 2-way = free)
        {
            const int n0 = (tid & 15) * 2, d0 = (tid >> 4) * 4;
            const float* v0 = Vh + (size_t)(kb + n0) * DKK + d0;
            f32x4 a = *(const f32x4*)v0;
            f32x4 b = *(const f32x4*)(v0 + DKK);
            #pragma unroll
            for (int i = 0; i < 4; ++i) {
                unsigned pk = ((unsigned)(unsigned short)f2bf(a[i])) |
                              ((unsigned)(unsigned short)f2bf(b[i]) << 16);
                *(unsigned*)&Vt[(d0 + i) * 40 + n0] = pk;
            }
        }
        __syncthreads();

        if (kb > qb + 15) continue;   // wave-uniform: beyond this wave's causal range

        // ---- S^T = K.Q^T : two key-halves (n 0..15, 16..31)
        f32x4 st0 = {0.f, 0.f, 0.f, 0.f}, st1 = {0.f, 0.f, 0.f, 0.f};
        {
            const bf16x8 k00 = *(const bf16x8*)&Kt[m16 * 72 + quad * 8];
            const bf16x8 k01 = *(const bf16x8*)&Kt[m16 * 72 + 32 + quad * 8];
            const bf16x8 k10 = *(const bf16x8*)&Kt[(16 + m16) * 72 + quad * 8];
            const bf16x8 k11 = *(const bf16x8*)&Kt[(16 + m16) * 72 + 32 + quad * 8];
            st0 = __builtin_amdgcn_mfma_f32_16x16x32_bf16(k00, qf[0], st0, 0, 0, 0);
            st0 = __builtin_amdgcn_mfma_f32_16x16x32_bf16(k01, qf[1], st0, 0, 0, 0);
            st1 = __builtin_amdgcn_mfma_f32_16x16x32_bf16(k10, qf[0], st1, 0, 0, 0);
            st1 = __builtin_amdgcn_mfma_f32_16x16x32_bf16(k11, qf[1], st1, 0, 0, 0);
        }

        // ---- scale to log2 domain + causal mask
        // lane holds S^T[n = 16*(i>>2) + 4*quad + (i&3)][m = m16]
        const float cs = 0.18033688011112042f;   // log2(e)/sqrt(64)
        float x[8];
        #pragma unroll
        for (int r = 0; r < 4; ++r) { x[r] = st0[r] * cs; x[4 + r] = st1[r] * cs; }
        // Mask needed whenever the tile's last key (kb+31) exceeds the wave's
        // FIRST query (qb) — NOT its last. (R1 bug: `> qb+15` left waves 1/3's
        // half-diagonal tiles unmasked -> future-key leak.)
        if (kb + 31 > qb) {
            #pragma unroll
            for (int i = 0; i < 8; ++i) {
                const int n = kb + (i >> 2) * 16 + quad * 4 + (i & 3);
                if (n > qrow) x[i] = -1e30f;
            }
        }

        // ---- online softmax (stats per m = lane&15; reduce regs then quads)
        float mx = x[0];
        #pragma unroll
        for (int i = 1; i < 8; ++i) mx = fmaxf(mx, x[i]);
        mx = fmaxf(mx, __shfl_xor(mx, 16));
        mx = fmaxf(mx, __shfl_xor(mx, 32));
        const float mnew  = fmaxf(mrun, mx);
        const float alpha = exp2f(mrun - mnew);
        float p[8], psum = 0.f;
        #pragma unroll
        for (int i = 0; i < 8; ++i) { p[i] = exp2f(x[i] - mnew); psum += p[i]; }
        psum += __shfl_xor(psum, 16);
        psum += __shfl_xor(psum, 32);
        lrun = lrun * alpha + psum;
        mrun = mnew;
        #pragma unroll
        for (int c = 0; c < 4; ++c) {
            #pragma unroll
            for (int r = 0; r < 4; ++r) acc[c][r] *= alpha;
        }

        // ---- P: C/D layout -> B-operand layout via per-wave LDS scratch
        short* ps = &Ps[w * 640];
        #pragma unroll
        for (int i = 0; i < 8; ++i)
            ps[m16 * 40 + (i >> 2) * 16 + quad * 4 + (i & 3)] = f2bf(p[i]);
        __threadfence_block();   // order wave-local LDS write->read
        const bf16x8 pf = *(const bf16x8*)&Ps[w * 640 + m16 * 40 + quad * 8];

        // ---- O^T += V^T . P^T  (4 d-chunks of 16)
        #pragma unroll
        for (int c = 0; c < 4; ++c) {
            const bf16x8 vf = *(const bf16x8*)&Vt[(c * 16 + m16) * 40 + quad * 8];
            acc[c] = __builtin_amdgcn_mfma_f32_16x16x32_bf16(vf, pf, acc[c], 0, 0, 0);
        }
    }

    // ---- epilogue: O[qrow][d] = acc / l ; lane holds d = 16c + 4*quad + r
    const float inv = 1.0f / lrun;
    float* op = Oh + (size_t)qrow * DKK;
    #pragma unroll
    for (int c = 0; c < 4; ++c) {
        #pragma unroll
        for (int r = 0; r < 4; ++r)
            op[c * 16 + quad * 4 + r] = acc[c][r] * inv;
    }
}

extern "C" void kernel_launch(void* const* d_in, const int* in_sizes, int n_in,
                              void* d_out, int out_size, void* d_ws, size_t ws_size,
                              hipStream_t stream) {
    // inputs: [0]=d_model(int), [1]=num_heads(int), [2]=Q, [3]=K, [4]=V, [5]=mask(bool, causal -> implicit)
    const float* Q = (const float*)d_in[2];
    const float* K = (const float*)d_in[3];
    const float* V = (const float*)d_in[4];
    float* O = (float*)d_out;
    (void)in_sizes; (void)n_in; (void)out_size; (void)d_ws; (void)ws_size;
    dim3 grid(SEQ / 64, 32 /* B*H */);
    fa_fwd<<<grid, 256, 0, stream>>>(Q, K, V, O);
}

// Round 3
// 700.590 us; speedup vs baseline: 1.0236x; 1.0236x over previous
//
#include <hip/hip_runtime.h>
#include <hip/hip_bf16.h>

// Causal MHA forward, B=2 H=16 S=2048 DK=64, fp32 in/out.
// Flash-attention, bf16 MFMA 16x16x32, S^T orientation:
//   S^T = K.Q^T  (A=K-frag, B=Q-frag)  -> per-q stats at lane&15
//   O^T = V^T.P^T (A=V^T-frag, B=P-frag) -> col=lane&15 matches stats
// R3: 64-key tiles (33 iters max, was 66), double-buffered LDS with register
// prefetch of tile t+1 during tile t compute, ONE barrier per iter, scale
// folded into Q frag. Tiles are 64-aligned == q-block size, so no wave ever
// skips a tile and only the final tile needs masking.

using bf16x8 = __attribute__((ext_vector_type(8))) short;
using bf16x4 = __attribute__((ext_vector_type(4))) short;
using f32x4  = __attribute__((ext_vector_type(4))) float;

#define SEQ  2048
#define DKK  64
#define KSTR 72   // LDS row stride in shorts (8-mod-64: b128 reads ~2-way)

__device__ __forceinline__ short f2bf(float f) {
    union { float f; unsigned u; } v; v.f = f;
    unsigned r = v.u + 0x7fffu + ((v.u >> 16) & 1u);   // RNE
    return (short)(r >> 16);
}

__global__ __launch_bounds__(256, 3)
void fa_fwd(const float* __restrict__ Qg, const float* __restrict__ Kg,
            const float* __restrict__ Vg, float* __restrict__ Og) {
    __shared__ short Kt[2][64 * KSTR];   // K tile: 64 keys x 64 d (bf16)
    __shared__ short Vt[2][64 * KSTR];   // V^T tile: 64 d x 64 keys (bf16)
    __shared__ short Ps[4][16 * KSTR];   // per-wave P scratch: 16 m x 64 n

    const int qblk = (int)gridDim.x - 1 - (int)blockIdx.x;  // heavy blocks first
    const int bh   = blockIdx.y;
    const int tid  = threadIdx.x;
    const int lane = tid & 63;
    const int w    = tid >> 6;
    const int m16  = lane & 15;
    const int quad = lane >> 4;

    const size_t hoff = (size_t)bh * SEQ * DKK;
    const float* Qh = Qg + hoff;
    const float* Kh = Kg + hoff;
    const float* Vh = Vg + hoff;
    float*       Oh = Og + hoff;

    const int qb   = qblk * 64 + 16 * w;   // wave's first q row
    const int qrow = qb + m16;

    // staging coordinates
    const int kn = tid >> 2, kc = tid & 3;             // K: row kn, 16-float chunk kc
    const int vn = (tid & 31) * 2, vd = (tid >> 5) * 8; // V: rows vn,vn+1, d vd..vd+7

    // Q fragment (B-operand layout), pre-scaled by log2(e)/sqrt(64)
    const float cs = 0.18033688011112042f;
    bf16x8 qf[2];
    {
        const float* qp = Qh + (size_t)qrow * DKK + quad * 8;
        #pragma unroll
        for (int h = 0; h < 2; ++h) {
            f32x4 a = *(const f32x4*)(qp + 32 * h);
            f32x4 b = *(const f32x4*)(qp + 32 * h + 4);
            bf16x8 f;
            f[0] = f2bf(a[0] * cs); f[1] = f2bf(a[1] * cs);
            f[2] = f2bf(a[2] * cs); f[3] = f2bf(a[3] * cs);
            f[4] = f2bf(b[0] * cs); f[5] = f2bf(b[1] * cs);
            f[6] = f2bf(b[2] * cs); f[7] = f2bf(b[3] * cs);
            qf[h] = f;
        }
    }

    float mrun = -1e30f, lrun = 0.f;
    f32x4 acc[4];
    {
        f32x4 z = {0.f, 0.f, 0.f, 0.f};
        #pragma unroll
        for (int c = 0; c < 4; ++c) acc[c] = z;
    }

    f32x4 kr[4], vr[4];
    auto load_tile = [&](int kb) {
        const float* kp = Kh + (size_t)(kb + kn) * DKK + kc * 16;
        #pragma unroll
        for (int i = 0; i < 4; ++i) kr[i] = *(const f32x4*)(kp + 4 * i);
        const float* vp = Vh + (size_t)(kb + vn) * DKK + vd;
        vr[0] = *(const f32x4*)vp;        vr[1] = *(const f32x4*)(vp + 4);
        vr[2] = *(const f32x4*)(vp + DKK); vr[3] = *(const f32x4*)(vp + DKK + 4);
    };
    auto store_tile = [&](int buf) {
        bf16x8 f0, f1;
        #pragma unroll
        for (int i = 0; i < 4; ++i) { f0[i] = f2bf(kr[0][i]); f0[4+i] = f2bf(kr[1][i]); }
        #pragma unroll
        for (int i = 0; i < 4; ++i) { f1[i] = f2bf(kr[2][i]); f1[4+i] = f2bf(kr[3][i]); }
        *(bf16x8*)&Kt[buf][kn * KSTR + kc * 16]     = f0;
        *(bf16x8*)&Kt[buf][kn * KSTR + kc * 16 + 8] = f1;
        #pragma unroll
        for (int i = 0; i < 8; ++i) {
            float a = (i < 4) ? vr[0][i] : vr[1][i - 4];
            float b = (i < 4) ? vr[2][i] : vr[3][i - 4];
            unsigned pk = ((unsigned)(unsigned short)f2bf(a)) |
                          ((unsigned)(unsigned short)f2bf(b) << 16);
            *(unsigned*)&Vt[buf][(vd + i) * KSTR + vn] = pk;
        }
    };

    const int T = qblk + 1;   // 64-key tiles covering keys 0..qblk*64+63
    load_tile(0);
    store_tile(0);
    __syncthreads();

    for (int t = 0; t < T; ++t) {
        const int cur = t & 1;
        const int kb  = t * 64;
        if (t + 1 < T) load_tile((t + 1) * 64);   // prefetch (covered by compute)

        // ---- S^T = K.Q^T : 4 key-chunks of 16, K=64 over two MFMAs each
        f32x4 st[4];
        #pragma unroll
        for (int c = 0; c < 4; ++c) {
            f32x4 z = {0.f, 0.f, 0.f, 0.f};
            const bf16x8 k0 = *(const bf16x8*)&Kt[cur][(16 * c + m16) * KSTR + quad * 8];
            const bf16x8 k1 = *(const bf16x8*)&Kt[cur][(16 * c + m16) * KSTR + 32 + quad * 8];
            z = __builtin_amdgcn_mfma_f32_16x16x32_bf16(k0, qf[0], z, 0, 0, 0);
            z = __builtin_amdgcn_mfma_f32_16x16x32_bf16(k1, qf[1], z, 0, 0, 0);
            st[c] = z;
        }

        // ---- causal mask (only final tile crosses the diagonal; already log2 domain)
        float x[16];
        #pragma unroll
        for (int c = 0; c < 4; ++c) {
            #pragma unroll
            for (int r = 0; r < 4; ++r) x[4 * c + r] = st[c][r];
        }
        if (t == T - 1) {
            #pragma unroll
            for (int c = 0; c < 4; ++c) {
                #pragma unroll
                for (int r = 0; r < 4; ++r) {
                    const int n = kb + 16 * c + quad * 4 + r;
                    if (n > qrow) x[4 * c + r] = -1e30f;
                }
            }
        }

        // ---- online softmax (per-q stats at lane&15; reduce regs then quads)
        float mx = x[0];
        #pragma unroll
        for (int i = 1; i < 16; ++i) mx = fmaxf(mx, x[i]);
        mx = fmaxf(mx, __shfl_xor(mx, 16));
        mx = fmaxf(mx, __shfl_xor(mx, 32));
        const float mnew  = fmaxf(mrun, mx);
        const float alpha = exp2f(mrun - mnew);
        float p[16], psum = 0.f;
        #pragma unroll
        for (int i = 0; i < 16; ++i) { p[i] = exp2f(x[i] - mnew); psum += p[i]; }
        psum += __shfl_xor(psum, 16);
        psum += __shfl_xor(psum, 32);
        lrun = lrun * alpha + psum;
        mrun = mnew;
        #pragma unroll
        for (int c = 0; c < 4; ++c) {
            #pragma unroll
            for (int r = 0; r < 4; ++r) acc[c][r] *= alpha;
        }

        // ---- P: C/D layout -> B-operand layout via per-wave LDS scratch
        short* ps = &Ps[w][0];
        #pragma unroll
        for (int c = 0; c < 4; ++c) {
            bf16x4 pk;
            pk[0] = f2bf(p[4*c]); pk[1] = f2bf(p[4*c+1]);
            pk[2] = f2bf(p[4*c+2]); pk[3] = f2bf(p[4*c+3]);
            *(bf16x4*)&ps[m16 * KSTR + 16 * c + quad * 4] = pk;
        }
        __threadfence_block();   // order wave-local LDS write->read
        bf16x8 pf[2];
        pf[0] = *(const bf16x8*)&ps[m16 * KSTR + quad * 8];
        pf[1] = *(const bf16x8*)&ps[m16 * KSTR + 32 + quad * 8];

        // ---- O^T += V^T . P^T  (4 d-chunks of 16, K=64 over two MFMAs)
        #pragma unroll
        for (int c = 0; c < 4; ++c) {
            const bf16x8 v0 = *(const bf16x8*)&Vt[cur][(16 * c + m16) * KSTR + quad * 8];
            const bf16x8 v1 = *(const bf16x8*)&Vt[cur][(16 * c + m16) * KSTR + 32 + quad * 8];
            acc[c] = __builtin_amdgcn_mfma_f32_16x16x32_bf16(v0, pf[0], acc[c], 0, 0, 0);
            acc[c] = __builtin_amdgcn_mfma_f32_16x16x32_bf16(v1, pf[1], acc[c], 0, 0, 0);
        }

        // ---- stage prefetched tile into the other buffer, then single barrier
        if (t + 1 < T) store_tile(cur ^ 1);
        __syncthreads();
    }

    // ---- epilogue: O[qrow][d] = acc / l ; lane holds d = 16c + 4*quad + r
    const float inv = 1.0f / lrun;
    float* op = Oh + (size_t)qrow * DKK;
    #pragma unroll
    for (int c = 0; c < 4; ++c) {
        #pragma unroll
        for (int r = 0; r < 4; ++r)
            op[c * 16 + quad * 4 + r] = acc[c][r] * inv;
    }
}

extern "C" void kernel_launch(void* const* d_in, const int* in_sizes, int n_in,
                              void* d_out, int out_size, void* d_ws, size_t ws_size,
                              hipStream_t stream) {
    // inputs: [0]=d_model, [1]=num_heads, [2]=Q, [3]=K, [4]=V, [5]=mask(causal -> implicit)
    const float* Q = (const float*)d_in[2];
    const float* K = (const float*)d_in[3];
    const float* V = (const float*)d_in[4];
    float* O = (float*)d_out;
    (void)in_sizes; (void)n_in; (void)out_size; (void)d_ws; (void)ws_size;
    dim3 grid(SEQ / 64, 32 /* B*H */);
    fa_fwd<<<grid, 256, 0, stream>>>(Q, K, V, O);
}

// Round 4
// 693.946 us; speedup vs baseline: 1.0334x; 1.0096x over previous
//
#include <hip/hip_runtime.h>
#include <hip/hip_bf16.h>

// Causal MHA forward, B=2 H=16 S=2048 DK=64, fp32 in/out.
// Flash-attention, bf16 MFMA 16x16x32, S^T orientation:
//   S^T = K.Q^T  (A=K-frag, B=Q-frag)  -> per-q stats at lane&15
//   O^T = V^T.P^T (A=V^T-frag, B=P-frag) -> col=lane&15 matches stats
// R4: kernel slice was VALU-issue bound on software bf16 cvt (~420 inst/wave-iter).
// All in-loop f32->bf16 now round-half-up: v_add 0x8000 + one v_perm per PAIR
// (1.5 inst/elem vs ~3), packs stored as uint/uint2/uint4. Epilogue b128 stores.

using bf16x8 = __attribute__((ext_vector_type(8))) short;
using f32x4  = __attribute__((ext_vector_type(4))) float;
using u32x4  = __attribute__((ext_vector_type(4))) unsigned;
using u32x2  = __attribute__((ext_vector_type(2))) unsigned;

#define SEQ  2048
#define DKK  64
#define KSTR 72   // LDS row stride in shorts

__device__ __forceinline__ short f2bf(float f) {   // RNE (used once, for Q)
    union { float f; unsigned u; } v; v.f = f;
    unsigned r = v.u + 0x7fffu + ((v.u >> 16) & 1u);
    return (short)(r >> 16);
}

// pack two floats -> two bf16 in one dword, round-half-up (add 0x8000, keep hi16)
// result: low16 = bf16(lo), high16 = bf16(hi)
__device__ __forceinline__ unsigned pkbf(float lo, float hi) {
    union { float f; unsigned u; } a, b; a.f = lo; b.f = hi;
    return __builtin_amdgcn_perm(b.u + 0x8000u, a.u + 0x8000u, 0x07060302u);
}

__device__ __forceinline__ float fexp2(float x) {
#if __has_builtin(__builtin_amdgcn_exp2f)
    return __builtin_amdgcn_exp2f(x);
#else
    return exp2f(x);
#endif
}

__global__ __launch_bounds__(256, 3)
void fa_fwd(const float* __restrict__ Qg, const float* __restrict__ Kg,
            const float* __restrict__ Vg, float* __restrict__ Og) {
    __shared__ short Kt[2][64 * KSTR];   // K tile: 64 keys x 64 d (bf16)
    __shared__ short Vt[2][64 * KSTR];   // V^T tile: 64 d x 64 keys (bf16)
    __shared__ short Ps[4][16 * KSTR];   // per-wave P scratch: 16 m x 64 n

    const int qblk = (int)gridDim.x - 1 - (int)blockIdx.x;  // heavy blocks first
    const int bh   = blockIdx.y;
    const int tid  = threadIdx.x;
    const int lane = tid & 63;
    const int w    = tid >> 6;
    const int m16  = lane & 15;
    const int quad = lane >> 4;

    const size_t hoff = (size_t)bh * SEQ * DKK;
    const float* Qh = Qg + hoff;
    const float* Kh = Kg + hoff;
    const float* Vh = Vg + hoff;
    float*       Oh = Og + hoff;

    const int qb   = qblk * 64 + 16 * w;   // wave's first q row
    const int qrow = qb + m16;

    // staging coordinates
    const int kn = tid >> 2, kc = tid & 3;              // K: row kn, 16-float chunk kc
    const int vn = (tid & 31) * 2, vd = (tid >> 5) * 8; // V: rows vn,vn+1, d vd..vd+7

    // Q fragment (B-operand layout), pre-scaled by log2(e)/sqrt(64); RNE (one-time)
    const float cs = 0.18033688011112042f;
    bf16x8 qf[2];
    {
        const float* qp = Qh + (size_t)qrow * DKK + quad * 8;
        #pragma unroll
        for (int h = 0; h < 2; ++h) {
            f32x4 a = *(const f32x4*)(qp + 32 * h);
            f32x4 b = *(const f32x4*)(qp + 32 * h + 4);
            bf16x8 f;
            f[0] = f2bf(a[0] * cs); f[1] = f2bf(a[1] * cs);
            f[2] = f2bf(a[2] * cs); f[3] = f2bf(a[3] * cs);
            f[4] = f2bf(b[0] * cs); f[5] = f2bf(b[1] * cs);
            f[6] = f2bf(b[2] * cs); f[7] = f2bf(b[3] * cs);
            qf[h] = f;
        }
    }

    float mrun = -1e30f, lrun = 0.f;
    f32x4 acc[4];
    {
        f32x4 z = {0.f, 0.f, 0.f, 0.f};
        #pragma unroll
        for (int c = 0; c < 4; ++c) acc[c] = z;
    }

    f32x4 kr[4], vr[4];
    auto load_tile = [&](int kb) {
        const float* kp = Kh + (size_t)(kb + kn) * DKK + kc * 16;
        #pragma unroll
        for (int i = 0; i < 4; ++i) kr[i] = *(const f32x4*)(kp + 4 * i);
        const float* vp = Vh + (size_t)(kb + vn) * DKK + vd;
        vr[0] = *(const f32x4*)vp;         vr[1] = *(const f32x4*)(vp + 4);
        vr[2] = *(const f32x4*)(vp + DKK); vr[3] = *(const f32x4*)(vp + DKK + 4);
    };
    auto store_tile = [&](int buf) {
        u32x4 A, B;
        A[0] = pkbf(kr[0][0], kr[0][1]); A[1] = pkbf(kr[0][2], kr[0][3]);
        A[2] = pkbf(kr[1][0], kr[1][1]); A[3] = pkbf(kr[1][2], kr[1][3]);
        B[0] = pkbf(kr[2][0], kr[2][1]); B[1] = pkbf(kr[2][2], kr[2][3]);
        B[2] = pkbf(kr[3][0], kr[3][1]); B[3] = pkbf(kr[3][2], kr[3][3]);
        *(u32x4*)&Kt[buf][kn * KSTR + kc * 16]     = A;
        *(u32x4*)&Kt[buf][kn * KSTR + kc * 16 + 8] = B;
        #pragma unroll
        for (int i = 0; i < 8; ++i) {
            const float a = (i < 4) ? vr[0][i] : vr[1][i - 4];   // key vn
            const float b = (i < 4) ? vr[2][i] : vr[3][i - 4];   // key vn+1
            *(unsigned*)&Vt[buf][(vd + i) * KSTR + vn] = pkbf(a, b);
        }
    };

    const int T = qblk + 1;   // 64-key tiles covering keys 0..qblk*64+63
    load_tile(0);
    store_tile(0);
    __syncthreads();

    for (int t = 0; t < T; ++t) {
        const int cur = t & 1;
        const int kb  = t * 64;
        if (t + 1 < T) load_tile((t + 1) * 64);   // prefetch (covered by compute)

        // ---- S^T = K.Q^T : 4 key-chunks of 16, K=64 over two MFMAs each
        f32x4 st[4];
        #pragma unroll
        for (int c = 0; c < 4; ++c) {
            f32x4 z = {0.f, 0.f, 0.f, 0.f};
            const bf16x8 k0 = *(const bf16x8*)&Kt[cur][(16 * c + m16) * KSTR + quad * 8];
            const bf16x8 k1 = *(const bf16x8*)&Kt[cur][(16 * c + m16) * KSTR + 32 + quad * 8];
            z = __builtin_amdgcn_mfma_f32_16x16x32_bf16(k0, qf[0], z, 0, 0, 0);
            z = __builtin_amdgcn_mfma_f32_16x16x32_bf16(k1, qf[1], z, 0, 0, 0);
            st[c] = z;
        }

        // ---- causal mask (only final tile crosses the diagonal; log2 domain already)
        float x[16];
        #pragma unroll
        for (int c = 0; c < 4; ++c) {
            #pragma unroll
            for (int r = 0; r < 4; ++r) x[4 * c + r] = st[c][r];
        }
        if (t == T - 1) {
            #pragma unroll
            for (int c = 0; c < 4; ++c) {
                #pragma unroll
                for (int r = 0; r < 4; ++r) {
                    const int n = kb + 16 * c + quad * 4 + r;
                    if (n > qrow) x[4 * c + r] = -1e30f;
                }
            }
        }

        // ---- online softmax (per-q stats at lane&15; reduce regs then quads)
        float mx = x[0];
        #pragma unroll
        for (int i = 1; i < 16; ++i) mx = fmaxf(mx, x[i]);
        mx = fmaxf(mx, __shfl_xor(mx, 16));
        mx = fmaxf(mx, __shfl_xor(mx, 32));
        const float mnew  = fmaxf(mrun, mx);
        const float alpha = fexp2(mrun - mnew);
        float p[16], psum = 0.f;
        #pragma unroll
        for (int i = 0; i < 16; ++i) { p[i] = fexp2(x[i] - mnew); psum += p[i]; }
        psum += __shfl_xor(psum, 16);
        psum += __shfl_xor(psum, 32);
        lrun = lrun * alpha + psum;
        mrun = mnew;
        #pragma unroll
        for (int c = 0; c < 4; ++c) {
            #pragma unroll
            for (int r = 0; r < 4; ++r) acc[c][r] *= alpha;
        }

        // ---- P: C/D layout -> B-operand layout via per-wave LDS scratch
        short* ps = &Ps[w][0];
        #pragma unroll
        for (int c = 0; c < 4; ++c) {
            u32x2 pk;
            pk[0] = pkbf(p[4 * c],     p[4 * c + 1]);
            pk[1] = pkbf(p[4 * c + 2], p[4 * c + 3]);
            *(u32x2*)&ps[m16 * KSTR + 16 * c + quad * 4] = pk;
        }
        __threadfence_block();   // order wave-local LDS write->read
        bf16x8 pf[2];
        pf[0] = *(const bf16x8*)&ps[m16 * KSTR + quad * 8];
        pf[1] = *(const bf16x8*)&ps[m16 * KSTR + 32 + quad * 8];

        // ---- O^T += V^T . P^T  (4 d-chunks of 16, K=64 over two MFMAs)
        #pragma unroll
        for (int c = 0; c < 4; ++c) {
            const bf16x8 v0 = *(const bf16x8*)&Vt[cur][(16 * c + m16) * KSTR + quad * 8];
            const bf16x8 v1 = *(const bf16x8*)&Vt[cur][(16 * c + m16) * KSTR + 32 + quad * 8];
            acc[c] = __builtin_amdgcn_mfma_f32_16x16x32_bf16(v0, pf[0], acc[c], 0, 0, 0);
            acc[c] = __builtin_amdgcn_mfma_f32_16x16x32_bf16(v1, pf[1], acc[c], 0, 0, 0);
        }

        // ---- stage prefetched tile into the other buffer, then single barrier
        if (t + 1 < T) store_tile(cur ^ 1);
        __syncthreads();
    }

    // ---- epilogue: O[qrow][d] = acc / l ; lane's 4 r-values are contiguous cols
    const float inv = 1.0f / lrun;
    float* op = Oh + (size_t)qrow * DKK;
    #pragma unroll
    for (int c = 0; c < 4; ++c) {
        f32x4 o;
        #pragma unroll
        for (int r = 0; r < 4; ++r) o[r] = acc[c][r] * inv;
        *(f32x4*)(op + c * 16 + quad * 4) = o;
    }
}

extern "C" void kernel_launch(void* const* d_in, const int* in_sizes, int n_in,
                              void* d_out, int out_size, void* d_ws, size_t ws_size,
                              hipStream_t stream) {
    // inputs: [0]=d_model, [1]=num_heads, [2]=Q, [3]=K, [4]=V, [5]=mask(causal -> implicit)
    const float* Q = (const float*)d_in[2];
    const float* K = (const float*)d_in[3];
    const float* V = (const float*)d_in[4];
    float* O = (float*)d_out;
    (void)in_sizes; (void)n_in; (void)out_size; (void)d_ws; (void)ws_size;
    dim3 grid(SEQ / 64, 32 /* B*H */);
    fa_fwd<<<grid, 256, 0, stream>>>(Q, K, V, O);
}

// Round 5
// 678.024 us; speedup vs baseline: 1.0577x; 1.0235x over previous
//
#include <hip/hip_runtime.h>
#include <hip/hip_bf16.h>

// Causal MHA forward, B=2 H=16 S=2048 DK=64, fp32 in/out.
// Flash-attention, bf16 MFMA 16x16x32, S^T orientation:
//   S^T = K.Q^T  (A=K-frag, B=Q-frag)  -> per-q stats at lane&15
//   O^T = V^T.P^T (A=V^T-frag, B=P-frag) -> col=lane&15 matches stats
// R5: slice was LDS-throughput bound (each wave re-reads full 8KB K + 8KB V
// tile per iter). Now each wave owns 32 q-rows (2 x 16-row chunks) sharing ONE
// set of K/V fragment reads; block covers 128 q. K/V LDS + global traffic per
// unit work halves; wave-iters halve. 512 blocks, 2/CU, all co-resident.

using bf16x8 = __attribute__((ext_vector_type(8))) short;
using f32x4  = __attribute__((ext_vector_type(4))) float;
using u32x4  = __attribute__((ext_vector_type(4))) unsigned;
using u32x2  = __attribute__((ext_vector_type(2))) unsigned;

#define SEQ  2048
#define DKK  64
#define KSTR 72   // LDS row stride in shorts

__device__ __forceinline__ short f2bf(float f) {   // RNE (used once, for Q)
    union { float f; unsigned u; } v; v.f = f;
    unsigned r = v.u + 0x7fffu + ((v.u >> 16) & 1u);
    return (short)(r >> 16);
}

// pack two floats -> two bf16 in one dword, round-half-up
__device__ __forceinline__ unsigned pkbf(float lo, float hi) {
    union { float f; unsigned u; } a, b; a.f = lo; b.f = hi;
    return __builtin_amdgcn_perm(b.u + 0x8000u, a.u + 0x8000u, 0x07060302u);
}

__global__ __launch_bounds__(256, 2)
void fa_fwd(const float* __restrict__ Qg, const float* __restrict__ Kg,
            const float* __restrict__ Vg, float* __restrict__ Og) {
    __shared__ short Kt[2][64 * KSTR];   // K tile: 64 keys x 64 d (bf16)
    __shared__ short Vt[2][64 * KSTR];   // V^T tile: 64 d x 64 keys (bf16)
    __shared__ short Ps[4][32 * KSTR];   // per-wave P scratch: 32 m x 64 n

    const int qblk = (int)gridDim.x - 1 - (int)blockIdx.x;  // heavy blocks first
    const int bh   = blockIdx.y;
    const int tid  = threadIdx.x;
    const int lane = tid & 63;
    const int w    = tid >> 6;
    const int m16  = lane & 15;
    const int quad = lane >> 4;

    const size_t hoff = (size_t)bh * SEQ * DKK;
    const float* Qh = Qg + hoff;
    const float* Kh = Kg + hoff;
    const float* Vh = Vg + hoff;
    float*       Oh = Og + hoff;

    const int qb = qblk * 128 + 32 * w;   // wave's first q row (owns 32 rows)

    // staging coordinates (64-key tile per iter)
    const int kn = tid >> 2, kc = tid & 3;              // K: row kn, 16-float chunk kc
    const int vn = (tid & 31) * 2, vd = (tid >> 5) * 8; // V: rows vn,vn+1, d vd..vd+7

    // Q fragments (B-operand layout), 2 chunks of 16 q-rows, scale folded in
    const float cs = 0.18033688011112042f;   // log2(e)/sqrt(64)
    bf16x8 qf[2][2];
    #pragma unroll
    for (int i = 0; i < 2; ++i) {
        const float* qp = Qh + (size_t)(qb + 16 * i + m16) * DKK + quad * 8;
        #pragma unroll
        for (int h = 0; h < 2; ++h) {
            f32x4 a = *(const f32x4*)(qp + 32 * h);
            f32x4 b = *(const f32x4*)(qp + 32 * h + 4);
            bf16x8 f;
            f[0] = f2bf(a[0] * cs); f[1] = f2bf(a[1] * cs);
            f[2] = f2bf(a[2] * cs); f[3] = f2bf(a[3] * cs);
            f[4] = f2bf(b[0] * cs); f[5] = f2bf(b[1] * cs);
            f[6] = f2bf(b[2] * cs); f[7] = f2bf(b[3] * cs);
            qf[i][h] = f;
        }
    }

    float mrun[2] = {-1e30f, -1e30f}, lrun[2] = {0.f, 0.f};
    f32x4 acc[2][4];
    {
        f32x4 z = {0.f, 0.f, 0.f, 0.f};
        #pragma unroll
        for (int i = 0; i < 2; ++i)
            #pragma unroll
            for (int c = 0; c < 4; ++c) acc[i][c] = z;
    }

    f32x4 kr[4], vr[4];
    auto load_tile = [&](int kb) {
        const float* kp = Kh + (size_t)(kb + kn) * DKK + kc * 16;
        #pragma unroll
        for (int i = 0; i < 4; ++i) kr[i] = *(const f32x4*)(kp + 4 * i);
        const float* vp = Vh + (size_t)(kb + vn) * DKK + vd;
        vr[0] = *(const f32x4*)vp;         vr[1] = *(const f32x4*)(vp + 4);
        vr[2] = *(const f32x4*)(vp + DKK); vr[3] = *(const f32x4*)(vp + DKK + 4);
    };
    auto store_tile = [&](int buf) {
        u32x4 A, B;
        A[0] = pkbf(kr[0][0], kr[0][1]); A[1] = pkbf(kr[0][2], kr[0][3]);
        A[2] = pkbf(kr[1][0], kr[1][1]); A[3] = pkbf(kr[1][2], kr[1][3]);
        B[0] = pkbf(kr[2][0], kr[2][1]); B[1] = pkbf(kr[2][2], kr[2][3]);
        B[2] = pkbf(kr[3][0], kr[3][1]); B[3] = pkbf(kr[3][2], kr[3][3]);
        *(u32x4*)&Kt[buf][kn * KSTR + kc * 16]     = A;
        *(u32x4*)&Kt[buf][kn * KSTR + kc * 16 + 8] = B;
        #pragma unroll
        for (int i = 0; i < 8; ++i) {
            const float a = (i < 4) ? vr[0][i] : vr[1][i - 4];   // key vn
            const float b = (i < 4) ? vr[2][i] : vr[3][i - 4];   // key vn+1
            *(unsigned*)&Vt[buf][(vd + i) * KSTR + vn] = pkbf(a, b);
        }
    };

    const int T = 2 * qblk + 2;   // 64-key tiles covering keys 0..qblk*128+127
    load_tile(0);
    store_tile(0);
    __syncthreads();

    for (int t = 0; t < T; ++t) {
        const int cur = t & 1;
        const int kb  = t * 64;
        if (t + 1 < T) load_tile((t + 1) * 64);   // prefetch (covered by compute)

        if (kb <= qb + 31) {   // wave-uniform: tile intersects this wave's range
            // ---- K fragments read ONCE, shared by both q-chunks
            bf16x8 kf[4][2];
            #pragma unroll
            for (int c = 0; c < 4; ++c) {
                kf[c][0] = *(const bf16x8*)&Kt[cur][(16 * c + m16) * KSTR + quad * 8];
                kf[c][1] = *(const bf16x8*)&Kt[cur][(16 * c + m16) * KSTR + 32 + quad * 8];
            }
            // ---- S^T = K.Q^T for both chunks
            f32x4 st0[4], st1[4];
            #pragma unroll
            for (int c = 0; c < 4; ++c) {
                f32x4 z0 = {0.f, 0.f, 0.f, 0.f}, z1 = {0.f, 0.f, 0.f, 0.f};
                z0 = __builtin_amdgcn_mfma_f32_16x16x32_bf16(kf[c][0], qf[0][0], z0, 0, 0, 0);
                z0 = __builtin_amdgcn_mfma_f32_16x16x32_bf16(kf[c][1], qf[0][1], z0, 0, 0, 0);
                z1 = __builtin_amdgcn_mfma_f32_16x16x32_bf16(kf[c][0], qf[1][0], z1, 0, 0, 0);
                z1 = __builtin_amdgcn_mfma_f32_16x16x32_bf16(kf[c][1], qf[1][1], z1, 0, 0, 0);
                st0[c] = z0; st1[c] = z1;
            }

            const bool domask = (kb + 63 > qb);
            short* ps = &Ps[w][0];

            // ---- per-chunk: mask, online softmax, P pack
            #pragma unroll
            for (int i = 0; i < 2; ++i) {
                const int qrow = qb + 16 * i + m16;
                float x[16];
                #pragma unroll
                for (int c = 0; c < 4; ++c) {
                    f32x4 s = i ? st1[c] : st0[c];
                    #pragma unroll
                    for (int r = 0; r < 4; ++r) x[4 * c + r] = s[r];
                }
                if (domask) {
                    #pragma unroll
                    for (int c = 0; c < 4; ++c)
                        #pragma unroll
                        for (int r = 0; r < 4; ++r) {
                            const int n = kb + 16 * c + quad * 4 + r;
                            if (n > qrow) x[4 * c + r] = -1e30f;
                        }
                }
                float mx = x[0];
                #pragma unroll
                for (int k = 1; k < 16; ++k) mx = fmaxf(mx, x[k]);
                mx = fmaxf(mx, __shfl_xor(mx, 16));
                mx = fmaxf(mx, __shfl_xor(mx, 32));
                const float mnew  = fmaxf(mrun[i], mx);
                const float alpha = exp2f(mrun[i] - mnew);
                float psum = 0.f;
                #pragma unroll
                for (int k = 0; k < 16; ++k) { x[k] = exp2f(x[k] - mnew); psum += x[k]; }
                psum += __shfl_xor(psum, 16);
                psum += __shfl_xor(psum, 32);
                lrun[i] = lrun[i] * alpha + psum;
                mrun[i] = mnew;
                #pragma unroll
                for (int c = 0; c < 4; ++c)
                    #pragma unroll
                    for (int r = 0; r < 4; ++r) acc[i][c][r] *= alpha;
                #pragma unroll
                for (int c = 0; c < 4; ++c) {
                    u32x2 pk;
                    pk[0] = pkbf(x[4 * c],     x[4 * c + 1]);
                    pk[1] = pkbf(x[4 * c + 2], x[4 * c + 3]);
                    *(u32x2*)&ps[(16 * i + m16) * KSTR + 16 * c + quad * 4] = pk;
                }
            }
            __threadfence_block();   // order wave-local LDS write->read

            bf16x8 pf[2][2];
            #pragma unroll
            for (int i = 0; i < 2; ++i) {
                pf[i][0] = *(const bf16x8*)&ps[(16 * i + m16) * KSTR + quad * 8];
                pf[i][1] = *(const bf16x8*)&ps[(16 * i + m16) * KSTR + 32 + quad * 8];
            }

            // ---- V fragments read ONCE, shared by both q-chunks
            #pragma unroll
            for (int c = 0; c < 4; ++c) {
                const bf16x8 v0 = *(const bf16x8*)&Vt[cur][(16 * c + m16) * KSTR + quad * 8];
                const bf16x8 v1 = *(const bf16x8*)&Vt[cur][(16 * c + m16) * KSTR + 32 + quad * 8];
                acc[0][c] = __builtin_amdgcn_mfma_f32_16x16x32_bf16(v0, pf[0][0], acc[0][c], 0, 0, 0);
                acc[0][c] = __builtin_amdgcn_mfma_f32_16x16x32_bf16(v1, pf[0][1], acc[0][c], 0, 0, 0);
                acc[1][c] = __builtin_amdgcn_mfma_f32_16x16x32_bf16(v0, pf[1][0], acc[1][c], 0, 0, 0);
                acc[1][c] = __builtin_amdgcn_mfma_f32_16x16x32_bf16(v1, pf[1][1], acc[1][c], 0, 0, 0);
            }
        }

        // ---- stage prefetched tile into the other buffer, then single barrier
        if (t + 1 < T) store_tile(cur ^ 1);
        __syncthreads();
    }

    // ---- epilogue: O[qrow][d] = acc / l
    #pragma unroll
    for (int i = 0; i < 2; ++i) {
        const float inv = 1.0f / lrun[i];
        float* op = Oh + (size_t)(qb + 16 * i + m16) * DKK;
        #pragma unroll
        for (int c = 0; c < 4; ++c) {
            f32x4 o;
            #pragma unroll
            for (int r = 0; r < 4; ++r) o[r] = acc[i][c][r] * inv;
            *(f32x4*)(op + c * 16 + quad * 4) = o;
        }
    }
}

extern "C" void kernel_launch(void* const* d_in, const int* in_sizes, int n_in,
                              void* d_out, int out_size, void* d_ws, size_t ws_size,
                              hipStream_t stream) {
    // inputs: [0]=d_model, [1]=num_heads, [2]=Q, [3]=K, [4]=V, [5]=mask(causal -> implicit)
    const float* Q = (const float*)d_in[2];
    const float* K = (const float*)d_in[3];
    const float* V = (const float*)d_in[4];
    float* O = (float*)d_out;
    (void)in_sizes; (void)n_in; (void)out_size; (void)d_ws; (void)ws_size;
    dim3 grid(SEQ / 128, 32 /* B*H */);
    fa_fwd<<<grid, 256, 0, stream>>>(Q, K, V, O);
}